// Round 7
// baseline (208.823 us; speedup 1.0000x reference)
//
#include <hip/hip_runtime.h>
#include <hip/hip_bf16.h>

// Problem: out[b,o] = sum_i inputs[b,i] * mean[indices[i,o]] + bias[o]
// B=2048, IN=4096, OUT=4096.  inputs f32, indices i32, mean f32, bias f32, out f32.

#define M_DIM 2048
#define K_DIM 4096
#define N_DIM 4096

#define BM 128
#define BN 256
#define BK 64
#define NT (K_DIM / BK)                       // 64 K-tiles
#define LDSA_BYTES (BM * BK * 2)              // 16384
#define LDSB_BYTES (BN * BK * 2)              // 32768
#define LDS_TILE   (LDSA_BYTES + LDSB_BYTES)  // 49152

typedef __attribute__((ext_vector_type(8))) short short8v;
typedef __attribute__((ext_vector_type(4))) float f32x4;

__device__ __forceinline__ unsigned short f2bf(float x) {
    unsigned u = __builtin_bit_cast(unsigned, x);
    u += 0x7fffu + ((u >> 16) & 1u);   // round-to-nearest-even
    return (unsigned short)(u >> 16);
}

__device__ __forceinline__ void gload_lds16(const void* g, void* l) {
    __builtin_amdgcn_global_load_lds(
        (const __attribute__((address_space(1))) void*)(uintptr_t)g,
        (__attribute__((address_space(3))) void*)(uintptr_t)l, 16, 0, 0);
}

// ---------------- Kernel 1: A f32 -> bf16 ----------------
__global__ void convert_a_kernel(const float* __restrict__ A,
                                 unsigned short* __restrict__ Abf) {
    int i = blockIdx.x * blockDim.x + threadIdx.x;
    const float4 v = ((const float4*)A)[i];
    ushort4 o;
    o.x = f2bf(v.x); o.y = f2bf(v.y); o.z = f2bf(v.z); o.w = f2bf(v.w);
    ((ushort4*)Abf)[i] = o;
}

// ------------- Kernel 2: decode + transpose: Wt[n][k] = bf16(mean[indices[k][n]]) -------------
__global__ void decode_transpose_kernel(const int* __restrict__ idx,
                                        const float* __restrict__ mean,
                                        unsigned short* __restrict__ Wt) {
    __shared__ float smean[K_DIM];
    __shared__ unsigned short tile[64][65];
    const int t = threadIdx.x;
    for (int i = t; i < K_DIM; i += 256) smean[i] = mean[i];
    __syncthreads();

    const int k0 = blockIdx.y * 64;
    const int n0 = blockIdx.x * 64;
    const int rb = t >> 4;
    const int cb = (t & 15) * 4;

    #pragma unroll
    for (int i = 0; i < 4; ++i) {
        const int r = rb + i * 16;
        const int4 v = *(const int4*)&idx[(size_t)(k0 + r) * N_DIM + n0 + cb];
        tile[cb + 0][r] = f2bf(smean[v.x]);
        tile[cb + 1][r] = f2bf(smean[v.y]);
        tile[cb + 2][r] = f2bf(smean[v.z]);
        tile[cb + 3][r] = f2bf(smean[v.w]);
    }
    __syncthreads();

    #pragma unroll
    for (int i = 0; i < 4; ++i) {
        const int r = rb + i * 16;
        ushort4 o;
        o.x = tile[r][cb + 0];
        o.y = tile[r][cb + 1];
        o.z = tile[r][cb + 2];
        o.w = tile[r][cb + 3];
        *(ushort4*)&Wt[(size_t)(n0 + r) * K_DIM + k0 + cb] = o;
    }
}

// ---------------- Kernel 3: bf16 GEMM  C = Abf @ Wt^T + bias ----------------
// Depth-1 REGISTER pipeline on top of the round-6 single-barrier structure:
//   tile t body: READF frags(t+1) from LDS  ||  STG6 tile t+3  ||  MFMA(t) on
//   registers loaded LAST tile  ->  lgkmcnt(0)  ->  vmcnt(6)  ->  barrier.
// MFMA(t) never waits on this tile's ds_reads (its operands drained a tile ago).
// Prefetch distance 3, 3 LDS buffers (b[t%3] recycled for tile t+3):
//   b(t+1): staged at t-2, landed by VM6 at end of t-1, READ at t,
//           overwritten at t+1 (safe: LGKM0+barrier at end of t drains reads).
// VM6 at end of tile t: outstanding = t+2's (<=6) + t+3's (6) -> waits until
// t+2's stage loads landed (needed by READF at t+1); t+3's stay in flight.

#define VM6   asm volatile("s_waitcnt vmcnt(6)" ::: "memory")
#define VM0   asm volatile("s_waitcnt vmcnt(0)" ::: "memory")
#define LGKM0 asm volatile("s_waitcnt lgkmcnt(0)" ::: "memory")

#define STG6(buf, t) do {                           \
    const int ko_ = (t) * BK;                       \
    gload_lds16(sA0 + ko_, (buf) + lA0);            \
    gload_lds16(sA1 + ko_, (buf) + lA1);            \
    gload_lds16(sB0 + ko_, (buf) + lB0);            \
    gload_lds16(sB1 + ko_, (buf) + lB1);            \
    gload_lds16(sB2 + ko_, (buf) + lB2);            \
    gload_lds16(sB3 + ko_, (buf) + lB3);            \
} while (0)

// Read a full tile's fragments: [0..3] = kk0 half, [4..7] = kk1 half (chunk
// c0^4 => per-thread byte delta so1 = +-64, bugfix from round 5).
#define READF(aS, bS, buf) do {                          \
    aS[0] = *(const short8v*)((buf) + rA0);              \
    aS[1] = *(const short8v*)((buf) + rA1);              \
    aS[2] = *(const short8v*)((buf) + rA2);              \
    aS[3] = *(const short8v*)((buf) + rA3);              \
    bS[0] = *(const short8v*)((buf) + rB0);              \
    bS[1] = *(const short8v*)((buf) + rB1);              \
    bS[2] = *(const short8v*)((buf) + rB2);              \
    bS[3] = *(const short8v*)((buf) + rB3);              \
    aS[4] = *(const short8v*)((buf) + rA0 + so1);        \
    aS[5] = *(const short8v*)((buf) + rA1 + so1);        \
    aS[6] = *(const short8v*)((buf) + rA2 + so1);        \
    aS[7] = *(const short8v*)((buf) + rA3 + so1);        \
    bS[4] = *(const short8v*)((buf) + rB0 + so1);        \
    bS[5] = *(const short8v*)((buf) + rB1 + so1);        \
    bS[6] = *(const short8v*)((buf) + rB2 + so1);        \
    bS[7] = *(const short8v*)((buf) + rB3 + so1);        \
} while (0)

#define MM1(aS, bS, ia, jb, i, j) \
    acc[i][j] = __builtin_amdgcn_mfma_f32_16x16x32_bf16(aS[ia], bS[jb], acc[i][j], 0, 0, 0)

#define MMALL(aS, bS) do {                                                           \
    MM1(aS,bS,0,0,0,0); MM1(aS,bS,0,1,0,1); MM1(aS,bS,0,2,0,2); MM1(aS,bS,0,3,0,3);  \
    MM1(aS,bS,1,0,1,0); MM1(aS,bS,1,1,1,1); MM1(aS,bS,1,2,1,2); MM1(aS,bS,1,3,1,3);  \
    MM1(aS,bS,2,0,2,0); MM1(aS,bS,2,1,2,1); MM1(aS,bS,2,2,2,2); MM1(aS,bS,2,3,2,3);  \
    MM1(aS,bS,3,0,3,0); MM1(aS,bS,3,1,3,1); MM1(aS,bS,3,2,3,2); MM1(aS,bS,3,3,3,3);  \
    MM1(aS,bS,4,4,0,0); MM1(aS,bS,4,5,0,1); MM1(aS,bS,4,6,0,2); MM1(aS,bS,4,7,0,3);  \
    MM1(aS,bS,5,4,1,0); MM1(aS,bS,5,5,1,1); MM1(aS,bS,5,6,1,2); MM1(aS,bS,5,7,1,3);  \
    MM1(aS,bS,6,4,2,0); MM1(aS,bS,6,5,2,1); MM1(aS,bS,6,6,2,2); MM1(aS,bS,6,7,2,3);  \
    MM1(aS,bS,7,4,3,0); MM1(aS,bS,7,5,3,1); MM1(aS,bS,7,6,3,2); MM1(aS,bS,7,7,3,3);  \
} while (0)

// One pipelined tile: cur frags (cA,cB) were read LAST tile; read nxt here.
#define BODY(bufRd, bufSt, tstg, cA, cB, nA, nB) do {  \
    READF(nA, nB, bufRd);                              \
    STG6(bufSt, tstg);                                 \
    __builtin_amdgcn_s_setprio(1);                     \
    MMALL(cA, cB);                                     \
    __builtin_amdgcn_s_setprio(0);                     \
    LGKM0;                                             \
    VM6;                                               \
    __builtin_amdgcn_s_barrier();                      \
} while (0)

__global__ __launch_bounds__(512, 2) void gemm_kernel(
        const unsigned short* __restrict__ Abf,   // [M][K]
        const unsigned short* __restrict__ Wt,    // [N][K]
        const float* __restrict__ bias,           // [N]
        float* __restrict__ C) {                  // [M][N]
    __shared__ __align__(128) char lds[3 * LDS_TILE];   // 144 KiB

    const int tid  = threadIdx.x;                 // 0..511
    const int lane = tid & 63;
    const int w    = tid >> 6;                    // 0..7
    const int wm   = w >> 2;                      // 0..1
    const int wn   = w & 3;                       // 0..3
    const int lr   = lane & 15;
    const int kq   = lane >> 4;                   // 0..3

    // XCD-chunked bijective block swizzle (256 blocks, 8 XCDs, 32/XCD)
    const int bid = blockIdx.x;
    const int wg  = (bid & 7) * 32 + (bid >> 3);
    const int m0  = (wg >> 4) * BM;               // 16 M-blocks
    const int n0  = (wg & 15) * BN;               // 16 N-blocks

    // ---- staging: slot p (16B): row = p>>3, swz chunk c = (p&7)^(row&7)
    const int pA0 = tid,        pA1 = 512 + tid;
    const int pB0 = tid,        pB1 = 512 + tid;
    const int pB2 = 1024 + tid, pB3 = 1536 + tid;
    const unsigned short* sA0 = Abf + (size_t)(m0 + (pA0 >> 3)) * K_DIM + 8 * ((pA0 & 7) ^ ((pA0 >> 3) & 7));
    const unsigned short* sA1 = Abf + (size_t)(m0 + (pA1 >> 3)) * K_DIM + 8 * ((pA1 & 7) ^ ((pA1 >> 3) & 7));
    const unsigned short* sB0 = Wt  + (size_t)(n0 + (pB0 >> 3)) * K_DIM + 8 * ((pB0 & 7) ^ ((pB0 >> 3) & 7));
    const unsigned short* sB1 = Wt  + (size_t)(n0 + (pB1 >> 3)) * K_DIM + 8 * ((pB1 & 7) ^ ((pB1 >> 3) & 7));
    const unsigned short* sB2 = Wt  + (size_t)(n0 + (pB2 >> 3)) * K_DIM + 8 * ((pB2 & 7) ^ ((pB2 >> 3) & 7));
    const unsigned short* sB3 = Wt  + (size_t)(n0 + (pB3 >> 3)) * K_DIM + 8 * ((pB3 & 7) ^ ((pB3 >> 3) & 7));
    const int lA0 = pA0 * 16,              lA1 = pA1 * 16;
    const int lB0 = LDSA_BYTES + pB0 * 16, lB1 = LDSA_BYTES + pB1 * 16;
    const int lB2 = LDSA_BYTES + pB2 * 16, lB3 = LDSA_BYTES + pB3 * 16;

    // ---- fragment read byte offsets; row&7 == lr&7.
    //      kk0 chunk c0 = kq^(lr&7); kk1 chunk = c0^4 => so1 = ((c0^4)-c0)*16.
    const int c0  = kq ^ (lr & 7);
    const int sc  = c0 * 16;
    const int so1 = ((c0 ^ 4) - c0) * 16;
    const int rA0 = (wm * 64 +  0 + lr) * 128 + sc;
    const int rA1 = (wm * 64 + 16 + lr) * 128 + sc;
    const int rA2 = (wm * 64 + 32 + lr) * 128 + sc;
    const int rA3 = (wm * 64 + 48 + lr) * 128 + sc;
    const int rB0 = LDSA_BYTES + (wn * 64 +  0 + lr) * 128 + sc;
    const int rB1 = LDSA_BYTES + (wn * 64 + 16 + lr) * 128 + sc;
    const int rB2 = LDSA_BYTES + (wn * 64 + 32 + lr) * 128 + sc;
    const int rB3 = LDSA_BYTES + (wn * 64 + 48 + lr) * 128 + sc;

    char* b0v = (char*)lds;
    char* b1v = (char*)lds + LDS_TILE;
    char* b2v = (char*)lds + 2 * LDS_TILE;

    f32x4 acc[4][4] = {};
    short8v aE[8], bE[8], aO[8], bO[8];

    // ---- prologue: stage tiles 0,1,2; wait 0,1; read frags(0) -> E ----
    STG6(b0v, 0);
    STG6(b1v, 1);
    STG6(b2v, 2);
    VM6;                                    // tiles 0,1 landed; 2 in flight
    __builtin_amdgcn_s_barrier();
    READF(aE, bE, b0v);
    LGKM0;                                  // drain so tile 0's STG(3)->b0 is safe
    __builtin_amdgcn_s_barrier();

    // ---- main loop: t = 0..59 (period 6 = 3 buffers x 2 parities) ----
    for (int tt = 0; tt < 10; ++tt) {
        const int t = tt * 6;
        BODY(b1v, b0v, t + 3, aE, bE, aO, bO);   // t+0 (E): read frags(t+1)->O
        BODY(b2v, b1v, t + 4, aO, bO, aE, bE);   // t+1 (O)
        BODY(b0v, b2v, t + 5, aE, bE, aO, bO);   // t+2 (E)
        BODY(b1v, b0v, t + 6, aO, bO, aE, bE);   // t+3 (O)
        BODY(b2v, b1v, t + 7, aE, bE, aO, bO);   // t+4 (E)
        BODY(b0v, b2v, t + 8, aO, bO, aE, bE);   // t+5 (O)
    }
    // t = 60 (E): read frags(61)->O, stage tile 63 -> b0
    BODY(b1v, b0v, 63, aE, bE, aO, bO);
    // t = 61 (O): read frags(62)->E; no stage; VM0 drains tile 63's stages
    READF(aE, bE, b2v);
    __builtin_amdgcn_s_setprio(1);
    MMALL(aO, bO);
    __builtin_amdgcn_s_setprio(0);
    LGKM0;
    VM0;
    __builtin_amdgcn_s_barrier();
    // t = 62 (E): read frags(63)->O; no stage
    READF(aO, bO, b0v);
    __builtin_amdgcn_s_setprio(1);
    MMALL(aE, bE);
    // t = 63 (O)
    MMALL(aO, bO);
    __builtin_amdgcn_s_setprio(0);

    // ---- epilogue: C[m][n] = acc + bias[n] ----
    #pragma unroll
    for (int j = 0; j < 4; ++j) {
        const int n = n0 + wn * 64 + j * 16 + lr;
        const float bv = bias[n];
        #pragma unroll
        for (int i = 0; i < 4; ++i) {
            const int mb = m0 + wm * 64 + i * 16 + kq * 4;
            #pragma unroll
            for (int q = 0; q < 4; ++q)
                C[(size_t)(mb + q) * N_DIM + n] = acc[i][j][q] + bv;
        }
    }
}

extern "C" void kernel_launch(void* const* d_in, const int* in_sizes, int n_in,
                              void* d_out, int out_size, void* d_ws, size_t ws_size,
                              hipStream_t stream) {
    const float* inputs  = (const float*)d_in[0];   // (2048, 4096) f32
    const int*   indices = (const int*)  d_in[1];   // (4096, 4096) i32
    const float* mean    = (const float*)d_in[2];   // (4096,) f32
    const float* bias    = (const float*)d_in[3];   // (4096,) f32
    float* out = (float*)d_out;                     // (2048, 4096) f32

    unsigned short* Abf = (unsigned short*)d_ws;                                      // 16 MiB
    unsigned short* Wt  = (unsigned short*)((char*)d_ws + (size_t)M_DIM * K_DIM * 2); // 32 MiB

    convert_a_kernel<<<(M_DIM * K_DIM / 4) / 256, 256, 0, stream>>>(inputs, Abf);
    decode_transpose_kernel<<<dim3(N_DIM / 64, K_DIM / 64), 256, 0, stream>>>(indices, mean, Wt);
    gemm_kernel<<<256, 512, 0, stream>>>(Abf, Wt, bias, out);
}